// Round 1
// baseline (494.425 us; speedup 1.0000x reference)
//
#include <hip/hip_runtime.h>
#include <math.h>

#define L_SEQ 1024
#define DM 128
#define JC 64
#define NCHUNK (L_SEQ / JC)

// workspace layout (floats)
#define OFF_KHAT 0                         // [L][4][48]  slots: 0..31 K, 32..43 Kg, 44 ck, 45 1.0, 46..47 0
#define OFF_QHAT (L_SEQ * 192)             // [L][4][48]  slots: 0..31 scale*Q, 32..43 w*Qg, 44 1.0, 45 cq
#define OFF_V    (OFF_QHAT + L_SEQ * 192)  // [L][128]    (h*32+d)
#define OFF_VG   (OFF_V + L_SEQ * DM)      // [L][48]     (h*12+p*3+x)
// total = 573440 floats = 2.29 MB

// ---------------- kernel 1: LN + projections + rotations + staging ----------------
__global__ __launch_bounds__(256) void ipa_prep(
    const float* __restrict__ single, const float* __restrict__ T,
    const float* __restrict__ w_C, const float* __restrict__ ln_g, const float* __restrict__ ln_b,
    const float* __restrict__ Wq, const float* __restrict__ Wk, const float* __restrict__ Wv,
    const float* __restrict__ Wqpt, const float* __restrict__ Wkpt, const float* __restrict__ Wvpt,
    float* __restrict__ ws)
{
    __shared__ float z_lds[4][128];
    __shared__ float proj[4][528];
    __shared__ float qg[4][4][4][3];
    __shared__ float kg[4][4][4][3];
    __shared__ float cq[4][4], ck[4][4];

    const int t = threadIdx.x;
    const int wv = t >> 6, lane = t & 63;
    const int i0 = blockIdx.x << 2;   // 4 rows per block, one per wave
    const int i = i0 + wv;

    // LayerNorm (one row per wave)
    float x0 = single[i*DM + lane];
    float x1 = single[i*DM + 64 + lane];
    float s = x0 + x1, s2 = x0*x0 + x1*x1;
    #pragma unroll
    for (int off = 1; off < 64; off <<= 1) { s += __shfl_xor(s, off); s2 += __shfl_xor(s2, off); }
    float mu = s * 0.0078125f;
    float var = s2 * 0.0078125f - mu*mu;
    float rs = rsqrtf(var + 1e-5f);
    z_lds[wv][lane]      = (x0 - mu) * rs * ln_g[lane]      + ln_b[lane];
    z_lds[wv][lane + 64] = (x1 - mu) * rs * ln_g[lane + 64] + ln_b[lane + 64];
    __syncthreads();

    // all 528 projection columns; each thread does a column for all 4 rows
    for (int cc = t; cc < 528; cc += 256) {
        const float* W; int col, ncol;
        if (cc < 128)      { W = Wq;   col = cc;       ncol = 128; }
        else if (cc < 256) { W = Wk;   col = cc - 128; ncol = 128; }
        else if (cc < 384) { W = Wv;   col = cc - 256; ncol = 128; }
        else if (cc < 432) { W = Wqpt; col = cc - 384; ncol = 48;  }
        else if (cc < 480) { W = Wkpt; col = cc - 432; ncol = 48;  }
        else               { W = Wvpt; col = cc - 480; ncol = 48;  }
        float a0 = 0.f, a1 = 0.f, a2 = 0.f, a3 = 0.f;
        #pragma unroll 8
        for (int k = 0; k < 128; ++k) {
            float w = W[k*ncol + col];
            a0 = fmaf(z_lds[0][k], w, a0);
            a1 = fmaf(z_lds[1][k], w, a1);
            a2 = fmaf(z_lds[2][k], w, a2);
            a3 = fmaf(z_lds[3][k], w, a3);
        }
        proj[0][cc] = a0; proj[1][cc] = a1; proj[2][cc] = a2; proj[3][cc] = a3;
    }
    __syncthreads();

    // rotations: thread t<64 -> (row, head, point)
    if (t < 64) {
        int r = t >> 4, h = (t >> 2) & 3, p = t & 3;
        int ii = i0 + r;
        float R[3][3], tt[3];
        #pragma unroll
        for (int x = 0; x < 3; ++x) {
            #pragma unroll
            for (int y = 0; y < 3; ++y) R[x][y] = T[ii*16 + x*4 + y];
            tt[x] = T[ii*16 + x*4 + 3];
        }
        int base = 384 + (h*4 + p)*3;
        float q0 = proj[r][base],    q1 = proj[r][base+1],  q2 = proj[r][base+2];
        float k0 = proj[r][base+48], k1 = proj[r][base+49], k2 = proj[r][base+50];
        float v0 = proj[r][base+96], v1 = proj[r][base+97], v2 = proj[r][base+98];
        #pragma unroll
        for (int x = 0; x < 3; ++x) {
            float qq = R[x][0]*q0 + R[x][1]*q1 + R[x][2]*q2 + tt[x];
            float kk = R[x][0]*k0 + R[x][1]*k1 + R[x][2]*k2 + tt[x];
            float vv = R[x][0]*v0 + R[x][1]*v1 + R[x][2]*v2 + tt[x];
            qg[r][h][p][x] = qq;
            kg[r][h][p][x] = kk;
            ws[OFF_VG + ii*48 + h*12 + p*3 + x] = vv;
        }
    }
    __syncthreads();

    // cq/ck = -0.5 * softplus(w_C[h]) * |Qg|^2 (resp |Kg|^2)
    if (t < 32) {
        int r = t >> 3, h = (t >> 1) & 3, isk = t & 1;
        float w = w_C[h];
        float wp = log1pf(__expf(w));
        float sq = 0.f;
        #pragma unroll
        for (int p = 0; p < 4; ++p)
            #pragma unroll
            for (int x = 0; x < 3; ++x) {
                float g = isk ? kg[r][h][p][x] : qg[r][h][p][x];
                sq += g*g;
            }
        float c = -0.5f * wp * sq;
        if (isk) ck[r][h] = c; else cq[r][h] = c;
    }
    __syncthreads();

    for (int idx = t; idx < 512; idx += 256) {
        int r = idx >> 7, d = idx & 127;
        ws[OFF_V + (size_t)(i0 + r)*DM + d] = proj[r][256 + d];
    }
    const float scale_attn = 0.17677669529663687f;  // 32^-0.5
    for (int idx = t; idx < 768; idx += 256) {
        int r = idx / 192, rem = idx % 192;
        int h = rem / 48, k = rem % 48;
        int ii = i0 + r;
        float w = w_C[h];
        float wp = log1pf(__expf(w));
        float kv, qv;
        if (k < 32) {
            kv = proj[r][128 + h*32 + k];
            qv = scale_attn * proj[r][h*32 + k];
        } else if (k < 44) {
            int e = k - 32;
            kv = kg[r][h][e/3][e%3];
            qv = wp * qg[r][h][e/3][e%3];
        } else if (k == 44) { kv = ck[r][h]; qv = 1.0f; }
        else if (k == 45)   { kv = 1.0f;    qv = cq[r][h]; }
        else                { kv = 0.f;     qv = 0.f; }
        ws[OFF_KHAT + (size_t)ii*192 + h*48 + k] = kv;
        ws[OFF_QHAT + (size_t)ii*192 + h*48 + k] = qv;
    }
}

// ---------------- kernel 2: fused flash-style IPA attention, 2 rows/block ----------------
__global__ __launch_bounds__(256, 2) void ipa_attn(
    const float* __restrict__ single, const float* __restrict__ pair,
    const float* __restrict__ T, const float* __restrict__ Wb,
    const float* __restrict__ Wout, const float* __restrict__ b_out,
    const float* __restrict__ ws, float* __restrict__ out)
{
    __shared__ __align__(16) float4 pair_lds[2][JC][16];     // xor-swizzled c4 ^= (j&7)
    __shared__ float bias_part[4][2][JC][5];                 // [c-quarter][row][j][h] (pad 5)
    __shared__ float p_lds[4][2][JC];                        // [h][row][j]
    __shared__ float alpha_lds[4][2];
    __shared__ float l_lds[4][2];
    __shared__ __align__(16) float4 qhat_lds[2][4][12];
    __shared__ __align__(16) float4 wb_lds[64];              // Wb[c][0..3]
    __shared__ float og_lds[2][4][12];
    __shared__ __align__(16) float u_lds[2][448];

    const int t = threadIdx.x;
    const int wv = t >> 6, lane = t & 63;
    const int i0 = blockIdx.x * 2;

    if (t < 96)       ((float4*)qhat_lds)[t] = ((const float4*)(ws + OFF_QHAT))[(size_t)i0*48 + t];
    else if (t < 160) wb_lds[t - 96] = ((const float4*)Wb)[t - 96];

    float m0 = -INFINITY, m1 = -INFINITY, l0 = 0.f, l1 = 0.f;
    float4 accp[2][4];   // o_pair, c = wv*16 + (lane&3)*4 + {0..3}, per head
    float4 accs[2];      // o_s,    d = (lane&7)*4 + {0..3}, head wv, j-split by lane>>3
    float4 accg[2];      // o_pt_g, f4 group lane&3 (<3), head wv, j-split by lane>>2
    #pragma unroll
    for (int r = 0; r < 2; ++r) {
        accs[r] = make_float4(0.f,0.f,0.f,0.f);
        accg[r] = make_float4(0.f,0.f,0.f,0.f);
        #pragma unroll
        for (int h = 0; h < 4; ++h) accp[r][h] = make_float4(0.f,0.f,0.f,0.f);
    }

    const float4* pair4 = (const float4*)pair;
    const float4* kh4   = (const float4*)(ws + OFF_KHAT);
    const float4* v4    = (const float4*)(ws + OFF_V);
    const float4* vg4   = (const float4*)(ws + OFF_VG);

    __syncthreads();

    for (int ch = 0; ch < NCHUNK; ++ch) {
        const int j0 = ch * JC;
        // ---- phase L: stage pair chunk (2 rows x 64 j x 64 c), coalesced, swizzled ----
        #pragma unroll
        for (int it = 0; it < 8; ++it) {
            int idx = t + 256*it;
            int c4 = idx & 15, rj = idx >> 4;
            int row = rj >> 6, j = rj & 63;
            float4 pv = pair4[((size_t)(i0 + row)*L_SEQ + j0 + j)*16 + c4];
            pair_lds[row][j][c4 ^ (j & 7)] = pv;
        }
        __syncthreads();

        // ---- phase B: bias partials; wave wv covers c in [16wv, 16wv+16) for all 4 heads ----
        {
            float b00=0,b01=0,b02=0,b03=0, b10=0,b11=0,b12=0,b13=0;
            #pragma unroll
            for (int c4p = 0; c4p < 4; ++c4p) {
                int c4 = (wv << 2) + c4p;
                float4 w0 = wb_lds[c4*4+0], w1 = wb_lds[c4*4+1], w2 = wb_lds[c4*4+2], w3 = wb_lds[c4*4+3];
                int sw = c4 ^ (lane & 7);
                float4 p0 = pair_lds[0][lane][sw];
                float4 p1 = pair_lds[1][lane][sw];
                b00 += p0.x*w0.x + p0.y*w1.x + p0.z*w2.x + p0.w*w3.x;
                b01 += p0.x*w0.y + p0.y*w1.y + p0.z*w2.y + p0.w*w3.y;
                b02 += p0.x*w0.z + p0.y*w1.z + p0.z*w2.z + p0.w*w3.z;
                b03 += p0.x*w0.w + p0.y*w1.w + p0.z*w2.w + p0.w*w3.w;
                b10 += p1.x*w0.x + p1.y*w1.x + p1.z*w2.x + p1.w*w3.x;
                b11 += p1.x*w0.y + p1.y*w1.y + p1.z*w2.y + p1.w*w3.y;
                b12 += p1.x*w0.z + p1.y*w1.z + p1.z*w2.z + p1.w*w3.z;
                b13 += p1.x*w0.w + p1.y*w1.w + p1.z*w2.w + p1.w*w3.w;
            }
            bias_part[wv][0][lane][0]=b00; bias_part[wv][0][lane][1]=b01;
            bias_part[wv][0][lane][2]=b02; bias_part[wv][0][lane][3]=b03;
            bias_part[wv][1][lane][0]=b10; bias_part[wv][1][lane][1]=b11;
            bias_part[wv][1][lane][2]=b12; bias_part[wv][1][lane][3]=b13;
        }
        __syncthreads();

        // ---- phase S: logits (48-wide dot) + online softmax; wave wv = head wv, lane = j ----
        {
            float4 kh[12];
            const float4* kp = kh4 + (size_t)(j0 + lane)*48 + wv*12;
            #pragma unroll
            for (int k4 = 0; k4 < 12; ++k4) kh[k4] = kp[k4];
            #pragma unroll
            for (int row = 0; row < 2; ++row) {
                float d = 0.f;
                #pragma unroll
                for (int k4 = 0; k4 < 12; ++k4) {
                    float4 q = qhat_lds[row][wv][k4];
                    d = fmaf(kh[k4].x, q.x, d); d = fmaf(kh[k4].y, q.y, d);
                    d = fmaf(kh[k4].z, q.z, d); d = fmaf(kh[k4].w, q.w, d);
                }
                float bias = bias_part[0][row][lane][wv] + bias_part[1][row][lane][wv]
                           + bias_part[2][row][lane][wv] + bias_part[3][row][lane][wv];
                float logit = d + bias;
                float cmax = logit;
                #pragma unroll
                for (int off = 1; off < 64; off <<= 1) cmax = fmaxf(cmax, __shfl_xor(cmax, off));
                float mo = row ? m1 : m0;
                float mn = fmaxf(mo, cmax);
                float alpha = __expf(mo - mn);
                float p = __expf(logit - mn);
                float ps = p;
                #pragma unroll
                for (int off = 1; off < 64; off <<= 1) ps += __shfl_xor(ps, off);
                if (row) { l1 = l1*alpha + ps; m1 = mn; } else { l0 = l0*alpha + ps; m0 = mn; }
                p_lds[wv][row][lane] = p;
                if (lane == 0) alpha_lds[wv][row] = alpha;
            }
        }
        __syncthreads();

        // ---- accumulate (rescale by alpha, then add new chunk) ----
        {
            float al[4][2];
            #pragma unroll
            for (int h = 0; h < 4; ++h) { al[h][0] = alpha_lds[h][0]; al[h][1] = alpha_lds[h][1]; }
            #pragma unroll
            for (int r = 0; r < 2; ++r) {
                #pragma unroll
                for (int h = 0; h < 4; ++h) {
                    float a = al[h][r];
                    accp[r][h].x *= a; accp[r][h].y *= a; accp[r][h].z *= a; accp[r][h].w *= a;
                }
                float a = al[wv][r];
                accs[r].x *= a; accs[r].y *= a; accs[r].z *= a; accs[r].w *= a;
                accg[r].x *= a; accg[r].y *= a; accg[r].z *= a; accg[r].w *= a;
            }
            // o_pair: wave wv's c-quarter, all heads
            {
                int c4p = lane & 3, jg = lane >> 2;
                #pragma unroll
                for (int jj = 0; jj < 4; ++jj) {
                    int j = jg + 16*jj;
                    int sw = ((wv << 2) + c4p) ^ (j & 7);
                    #pragma unroll
                    for (int r = 0; r < 2; ++r) {
                        float4 pv = pair_lds[r][j][sw];
                        float pw0 = p_lds[0][r][j], pw1 = p_lds[1][r][j];
                        float pw2 = p_lds[2][r][j], pw3 = p_lds[3][r][j];
                        accp[r][0].x = fmaf(pw0, pv.x, accp[r][0].x); accp[r][0].y = fmaf(pw0, pv.y, accp[r][0].y);
                        accp[r][0].z = fmaf(pw0, pv.z, accp[r][0].z); accp[r][0].w = fmaf(pw0, pv.w, accp[r][0].w);
                        accp[r][1].x = fmaf(pw1, pv.x, accp[r][1].x); accp[r][1].y = fmaf(pw1, pv.y, accp[r][1].y);
                        accp[r][1].z = fmaf(pw1, pv.z, accp[r][1].z); accp[r][1].w = fmaf(pw1, pv.w, accp[r][1].w);
                        accp[r][2].x = fmaf(pw2, pv.x, accp[r][2].x); accp[r][2].y = fmaf(pw2, pv.y, accp[r][2].y);
                        accp[r][2].z = fmaf(pw2, pv.z, accp[r][2].z); accp[r][2].w = fmaf(pw2, pv.w, accp[r][2].w);
                        accp[r][3].x = fmaf(pw3, pv.x, accp[r][3].x); accp[r][3].y = fmaf(pw3, pv.y, accp[r][3].y);
                        accp[r][3].z = fmaf(pw3, pv.z, accp[r][3].z); accp[r][3].w = fmaf(pw3, pv.w, accp[r][3].w);
                    }
                }
            }
            // o_s: head wv
            {
                int d4 = lane & 7, jg = lane >> 3;
                #pragma unroll
                for (int jj = 0; jj < 8; ++jj) {
                    int j = jg + 8*jj;
                    float4 vv = v4[(size_t)(j0 + j)*32 + wv*8 + d4];
                    float pa = p_lds[wv][0][j], pb = p_lds[wv][1][j];
                    accs[0].x = fmaf(pa, vv.x, accs[0].x); accs[0].y = fmaf(pa, vv.y, accs[0].y);
                    accs[0].z = fmaf(pa, vv.z, accs[0].z); accs[0].w = fmaf(pa, vv.w, accs[0].w);
                    accs[1].x = fmaf(pb, vv.x, accs[1].x); accs[1].y = fmaf(pb, vv.y, accs[1].y);
                    accs[1].z = fmaf(pb, vv.z, accs[1].z); accs[1].w = fmaf(pb, vv.w, accs[1].w);
                }
            }
            // o_pt_g: head wv
            {
                int g4 = lane & 3, jg = lane >> 2;
                #pragma unroll
                for (int jj = 0; jj < 4; ++jj) {
                    int j = jg + 16*jj;
                    float4 gv = make_float4(0.f,0.f,0.f,0.f);
                    if (g4 < 3) gv = vg4[(size_t)(j0 + j)*12 + wv*3 + g4];
                    float pa = p_lds[wv][0][j], pb = p_lds[wv][1][j];
                    accg[0].x = fmaf(pa, gv.x, accg[0].x); accg[0].y = fmaf(pa, gv.y, accg[0].y);
                    accg[0].z = fmaf(pa, gv.z, accg[0].z); accg[0].w = fmaf(pa, gv.w, accg[0].w);
                    accg[1].x = fmaf(pb, gv.x, accg[1].x); accg[1].y = fmaf(pb, gv.y, accg[1].y);
                    accg[1].z = fmaf(pb, gv.z, accg[1].z); accg[1].w = fmaf(pb, gv.w, accg[1].w);
                }
            }
        }
        __syncthreads();
    }

    // ---- epilogue: cross-lane reductions ----
    #pragma unroll
    for (int r = 0; r < 2; ++r) {
        #pragma unroll
        for (int h = 0; h < 4; ++h) {
            #pragma unroll
            for (int off = 4; off < 64; off <<= 1) {
                accp[r][h].x += __shfl_xor(accp[r][h].x, off);
                accp[r][h].y += __shfl_xor(accp[r][h].y, off);
                accp[r][h].z += __shfl_xor(accp[r][h].z, off);
                accp[r][h].w += __shfl_xor(accp[r][h].w, off);
            }
        }
        #pragma unroll
        for (int off = 8; off < 64; off <<= 1) {
            accs[r].x += __shfl_xor(accs[r].x, off); accs[r].y += __shfl_xor(accs[r].y, off);
            accs[r].z += __shfl_xor(accs[r].z, off); accs[r].w += __shfl_xor(accs[r].w, off);
        }
        #pragma unroll
        for (int off = 4; off < 64; off <<= 1) {
            accg[r].x += __shfl_xor(accg[r].x, off); accg[r].y += __shfl_xor(accg[r].y, off);
            accg[r].z += __shfl_xor(accg[r].z, off); accg[r].w += __shfl_xor(accg[r].w, off);
        }
    }
    if (lane == 0) { l_lds[wv][0] = l0; l_lds[wv][1] = l1; }
    __syncthreads();
    float invl[4][2];
    #pragma unroll
    for (int h = 0; h < 4; ++h) { invl[h][0] = 1.f / l_lds[h][0]; invl[h][1] = 1.f / l_lds[h][1]; }

    if (lane < 8) {
        #pragma unroll
        for (int r = 0; r < 2; ++r) {
            float sc = invl[wv][r];
            int base = wv*32 + lane*4;
            u_lds[r][base+0] = accs[r].x*sc; u_lds[r][base+1] = accs[r].y*sc;
            u_lds[r][base+2] = accs[r].z*sc; u_lds[r][base+3] = accs[r].w*sc;
        }
    }
    if (lane < 4) {
        #pragma unroll
        for (int r = 0; r < 2; ++r)
            #pragma unroll
            for (int h = 0; h < 4; ++h) {
                float sc = invl[h][r];
                int base = 128 + h*64 + wv*16 + lane*4;
                u_lds[r][base+0] = accp[r][h].x*sc; u_lds[r][base+1] = accp[r][h].y*sc;
                u_lds[r][base+2] = accp[r][h].z*sc; u_lds[r][base+3] = accp[r][h].w*sc;
            }
    }
    if (lane < 3) {
        #pragma unroll
        for (int r = 0; r < 2; ++r) {
            float sc = invl[wv][r];
            og_lds[r][wv][lane*4+0] = accg[r].x*sc; og_lds[r][wv][lane*4+1] = accg[r].y*sc;
            og_lds[r][wv][lane*4+2] = accg[r].z*sc; og_lds[r][wv][lane*4+3] = accg[r].w*sc;
        }
    }
    __syncthreads();

    // inverse-rotate o_pt_g, norms
    if (t < 32) {
        int r = t >> 4, idx = t & 15, h = idx >> 2, p = idx & 3;
        int ii = i0 + r;
        float R[3][3], tt[3];
        #pragma unroll
        for (int x = 0; x < 3; ++x) {
            #pragma unroll
            for (int y = 0; y < 3; ++y) R[x][y] = T[ii*16 + x*4 + y];
            tt[x] = T[ii*16 + x*4 + 3];
        }
        float v0 = og_lds[r][h][p*3+0] - tt[0];
        float v1 = og_lds[r][h][p*3+1] - tt[1];
        float v2 = og_lds[r][h][p*3+2] - tt[2];
        float n2 = 0.f;
        #pragma unroll
        for (int x = 0; x < 3; ++x) {
            float o = R[0][x]*v0 + R[1][x]*v1 + R[2][x]*v2;
            u_lds[r][384 + h*12 + p*3 + x] = o;
            n2 += o*o;
        }
        u_lds[r][432 + h*4 + p] = sqrtf(n2);
    }
    __syncthreads();

    // final projection: out = single + u @ Wout + b_out
    {
        int r = t >> 7, d = t & 127;
        int ii = i0 + r;
        float acc = single[ii*DM + d] + b_out[d];
        const float4* u4 = (const float4*)u_lds[r];
        #pragma unroll 4
        for (int k4 = 0; k4 < 112; ++k4) {
            float4 u = u4[k4];
            const float* wp = Wout + (size_t)(k4*4)*128 + d;
            acc = fmaf(u.x, wp[0],   acc);
            acc = fmaf(u.y, wp[128], acc);
            acc = fmaf(u.z, wp[256], acc);
            acc = fmaf(u.w, wp[384], acc);
        }
        out[ii*DM + d] = acc;
    }
}

extern "C" void kernel_launch(void* const* d_in, const int* in_sizes, int n_in,
                              void* d_out, int out_size, void* d_ws, size_t ws_size,
                              hipStream_t stream)
{
    const float* single = (const float*)d_in[0];
    const float* pair   = (const float*)d_in[1];
    const float* T      = (const float*)d_in[2];
    const float* w_C    = (const float*)d_in[3];
    const float* ln_g   = (const float*)d_in[4];
    const float* ln_b   = (const float*)d_in[5];
    const float* Wq     = (const float*)d_in[6];
    const float* Wk     = (const float*)d_in[7];
    const float* Wv     = (const float*)d_in[8];
    const float* Wqpt   = (const float*)d_in[9];
    const float* Wkpt   = (const float*)d_in[10];
    const float* Wvpt   = (const float*)d_in[11];
    const float* Wb     = (const float*)d_in[12];
    const float* Wout   = (const float*)d_in[13];
    const float* b_out  = (const float*)d_in[14];
    float* out = (float*)d_out;
    float* ws  = (float*)d_ws;

    ipa_prep<<<256, 256, 0, stream>>>(single, T, w_C, ln_g, ln_b, Wq, Wk, Wv, Wqpt, Wkpt, Wvpt, ws);
    ipa_attn<<<512, 256, 0, stream>>>(single, pair, T, Wb, Wout, b_out, ws, out);
}

// Round 2
// 473.760 us; speedup vs baseline: 1.0436x; 1.0436x over previous
//
#include <hip/hip_runtime.h>
#include <math.h>

#define L_SEQ 1024
#define DM 128
#define JC 32
#define NCH (L_SEQ / JC)

// workspace layout (floats)
#define OFF_KHAT 0                         // [L][4][48]  slots: 0..31 K, 32..43 Kg, 44 ck, 45 1.0, 46..47 0
#define OFF_QHAT (L_SEQ * 192)             // [L][4][48]  slots: 0..31 scale*Q, 32..43 w*Qg, 44 1.0, 45 cq
#define OFF_V    (OFF_QHAT + L_SEQ * 192)  // [L][128]    (h*32+d)
#define OFF_VG   (OFF_V + L_SEQ * DM)      // [L][48]     (h*12+p*3+x)

typedef __attribute__((address_space(1))) const void* gas_t;
typedef __attribute__((address_space(3))) void* las_t;

__device__ __forceinline__ void async16(const float4* g, float4* l) {
    __builtin_amdgcn_global_load_lds((gas_t)g, (las_t)l, 16, 0, 0);
}
// raw barrier: drain LDS ops only; do NOT drain vmcnt (keeps async prefetch in flight)
#define ASYNC_BAR() asm volatile("s_waitcnt lgkmcnt(0)\n\ts_barrier" ::: "memory")

// ---------------- kernel 1: LN + projections + rotations + staging ----------------
__global__ __launch_bounds__(256) void ipa_prep(
    const float* __restrict__ single, const float* __restrict__ T,
    const float* __restrict__ w_C, const float* __restrict__ ln_g, const float* __restrict__ ln_b,
    const float* __restrict__ Wq, const float* __restrict__ Wk, const float* __restrict__ Wv,
    const float* __restrict__ Wqpt, const float* __restrict__ Wkpt, const float* __restrict__ Wvpt,
    float* __restrict__ ws)
{
    __shared__ float z_lds[4][128];
    __shared__ float proj[4][528];
    __shared__ float qg[4][4][4][3];
    __shared__ float kg[4][4][4][3];
    __shared__ float cq[4][4], ck[4][4];

    const int t = threadIdx.x;
    const int wv = t >> 6, lane = t & 63;
    const int i0 = blockIdx.x << 2;
    const int i = i0 + wv;

    float x0 = single[i*DM + lane];
    float x1 = single[i*DM + 64 + lane];
    float s = x0 + x1, s2 = x0*x0 + x1*x1;
    #pragma unroll
    for (int off = 1; off < 64; off <<= 1) { s += __shfl_xor(s, off); s2 += __shfl_xor(s2, off); }
    float mu = s * 0.0078125f;
    float var = s2 * 0.0078125f - mu*mu;
    float rs = rsqrtf(var + 1e-5f);
    z_lds[wv][lane]      = (x0 - mu) * rs * ln_g[lane]      + ln_b[lane];
    z_lds[wv][lane + 64] = (x1 - mu) * rs * ln_g[lane + 64] + ln_b[lane + 64];
    __syncthreads();

    for (int cc = t; cc < 528; cc += 256) {
        const float* W; int col, ncol;
        if (cc < 128)      { W = Wq;   col = cc;       ncol = 128; }
        else if (cc < 256) { W = Wk;   col = cc - 128; ncol = 128; }
        else if (cc < 384) { W = Wv;   col = cc - 256; ncol = 128; }
        else if (cc < 432) { W = Wqpt; col = cc - 384; ncol = 48;  }
        else if (cc < 480) { W = Wkpt; col = cc - 432; ncol = 48;  }
        else               { W = Wvpt; col = cc - 480; ncol = 48;  }
        float a0 = 0.f, a1 = 0.f, a2 = 0.f, a3 = 0.f;
        #pragma unroll 8
        for (int k = 0; k < 128; ++k) {
            float w = W[k*ncol + col];
            a0 = fmaf(z_lds[0][k], w, a0);
            a1 = fmaf(z_lds[1][k], w, a1);
            a2 = fmaf(z_lds[2][k], w, a2);
            a3 = fmaf(z_lds[3][k], w, a3);
        }
        proj[0][cc] = a0; proj[1][cc] = a1; proj[2][cc] = a2; proj[3][cc] = a3;
    }
    __syncthreads();

    if (t < 64) {
        int r = t >> 4, h = (t >> 2) & 3, p = t & 3;
        int ii = i0 + r;
        float R[3][3], tt[3];
        #pragma unroll
        for (int x = 0; x < 3; ++x) {
            #pragma unroll
            for (int y = 0; y < 3; ++y) R[x][y] = T[ii*16 + x*4 + y];
            tt[x] = T[ii*16 + x*4 + 3];
        }
        int base = 384 + (h*4 + p)*3;
        float q0 = proj[r][base],    q1 = proj[r][base+1],  q2 = proj[r][base+2];
        float k0 = proj[r][base+48], k1 = proj[r][base+49], k2 = proj[r][base+50];
        float v0 = proj[r][base+96], v1 = proj[r][base+97], v2 = proj[r][base+98];
        #pragma unroll
        for (int x = 0; x < 3; ++x) {
            float qq = R[x][0]*q0 + R[x][1]*q1 + R[x][2]*q2 + tt[x];
            float kk = R[x][0]*k0 + R[x][1]*k1 + R[x][2]*k2 + tt[x];
            float vv = R[x][0]*v0 + R[x][1]*v1 + R[x][2]*v2 + tt[x];
            qg[r][h][p][x] = qq;
            kg[r][h][p][x] = kk;
            ws[OFF_VG + ii*48 + h*12 + p*3 + x] = vv;
        }
    }
    __syncthreads();

    if (t < 32) {
        int r = t >> 3, h = (t >> 1) & 3, isk = t & 1;
        float w = w_C[h];
        float wp = log1pf(__expf(w));
        float sq = 0.f;
        #pragma unroll
        for (int p = 0; p < 4; ++p)
            #pragma unroll
            for (int x = 0; x < 3; ++x) {
                float g = isk ? kg[r][h][p][x] : qg[r][h][p][x];
                sq += g*g;
            }
        float c = -0.5f * wp * sq;
        if (isk) ck[r][h] = c; else cq[r][h] = c;
    }
    __syncthreads();

    for (int idx = t; idx < 512; idx += 256) {
        int r = idx >> 7, d = idx & 127;
        ws[OFF_V + (size_t)(i0 + r)*DM + d] = proj[r][256 + d];
    }
    const float scale_attn = 0.17677669529663687f;  // 32^-0.5
    for (int idx = t; idx < 768; idx += 256) {
        int r = idx / 192, rem = idx % 192;
        int h = rem / 48, k = rem % 48;
        int ii = i0 + r;
        float w = w_C[h];
        float wp = log1pf(__expf(w));
        float kv, qv;
        if (k < 32) {
            kv = proj[r][128 + h*32 + k];
            qv = scale_attn * proj[r][h*32 + k];
        } else if (k < 44) {
            int e = k - 32;
            kv = kg[r][h][e/3][e%3];
            qv = wp * qg[r][h][e/3][e%3];
        } else if (k == 44) { kv = ck[r][h]; qv = 1.0f; }
        else if (k == 45)   { kv = 1.0f;    qv = cq[r][h]; }
        else                { kv = 0.f;     qv = 0.f; }
        ws[OFF_KHAT + (size_t)ii*192 + h*48 + k] = kv;
        ws[OFF_QHAT + (size_t)ii*192 + h*48 + k] = qv;
    }
}

// ---------------- kernel 2: fused IPA attention, dbuf async pipeline ----------------
__global__ __launch_bounds__(256, 2) void ipa_attn(
    const float* __restrict__ single, const float* __restrict__ pair,
    const float* __restrict__ T, const float* __restrict__ Wb,
    const float* __restrict__ Wout, const float* __restrict__ b_out,
    const float* __restrict__ ws, float* __restrict__ out)
{
    __shared__ __align__(16) float4 pair_lds[2][2][JC][16]; // [buf][row][j][slot] swizzled slot=c4^(j&7), 32 KB
    __shared__ float bias_part[4][2][JC][5];                // [c-quarter][row][j][h] pad 5
    __shared__ float p_lds[4][2][JC];                       // [h][row][j]
    __shared__ float alpha_lds[4][2];
    __shared__ float l_lds[4][2];
    __shared__ __align__(16) float4 qhat_lds[2][4][12];
    __shared__ __align__(16) float4 wb_lds[64];
    __shared__ float og_lds[2][4][12];
    __shared__ __align__(16) float u_lds[2][448];

    const int t = threadIdx.x;
    const int wv = t >> 6, lane = t & 63;
    const int i0 = blockIdx.x * 2;

    if (t < 96)       ((float4*)qhat_lds)[t] = ((const float4*)(ws + OFF_QHAT))[(size_t)i0*48 + t];
    else if (t < 160) wb_lds[t - 96] = ((const float4*)Wb)[t - 96];

    // phase-role indices
    const int r_b = lane >> 5, j_b = lane & 31;   // phase B/S: lane = r*32+j ... B uses (r_b,j_b)
    const int r_s = lane & 1,  j_s = lane >> 1;   // phase S: interleaved rows (coalesced kh loads)
    const int d4  = lane & 7,  jg_s = lane >> 3;  // o_s
    const int c4p = lane >> 4, jg_p = lane & 15;  // o_pair
    const int g4  = lane & 3,  jg_g = lane >> 2;  // o_pt_g
    const int g4c = (g4 < 3) ? g4 : 0;

    float m_run = -INFINITY, l_run = 0.f;         // per-lane (its row) softmax state
    float4 accp[2][4];   // o_pair: c4 = wv*4 + c4p, per (row,head)
    float4 accs[2];      // o_s: d = wv*32 + d4*4+e, j-split by jg_s
    float4 accg[2];      // o_pt_g: float4-group g4 (<3), head wv, j-split by jg_g
    #pragma unroll
    for (int r = 0; r < 2; ++r) {
        accs[r] = make_float4(0.f,0.f,0.f,0.f);
        accg[r] = make_float4(0.f,0.f,0.f,0.f);
        #pragma unroll
        for (int h = 0; h < 4; ++h) accp[r][h] = make_float4(0.f,0.f,0.f,0.f);
    }

    const float4* pair4 = (const float4*)pair;
    const float4* kh4   = (const float4*)(ws + OFF_KHAT);
    const float4* v4    = (const float4*)(ws + OFF_V);
    const float4* vg4   = (const float4*)(ws + OFF_VG);
    float4* plds_flat   = &pair_lds[0][0][0][0];

    // issue chunk 0 -> buf 0 (4 async16 per thread; LDS dest lane-linear, global swizzle-permuted)
    {
        #pragma unroll
        for (int it = 0; it < 4; ++it) {
            int idx = it*256 + t;
            int row = idx >> 9, j = (idx >> 4) & 31, slot = idx & 15;
            int c4 = slot ^ (j & 7);
            async16(pair4 + ((size_t)(i0 + row)*L_SEQ + j)*16 + c4, plds_flat + idx);
        }
    }

    for (int ch = 0; ch < NCH; ++ch) {
        const int cur = ch & 1;
        const int j0 = ch * JC;

        ASYNC_BAR();   // prev iter's reads of buf[1-cur] done; (ch=0: qhat/wb published)
        if (ch + 1 < NCH) {
            const int jn = (ch + 1) * JC;
            #pragma unroll
            for (int it = 0; it < 4; ++it) {
                int idx = it*256 + t;
                int row = idx >> 9, j = (idx >> 4) & 31, slot = idx & 15;
                int c4 = slot ^ (j & 7);
                async16(pair4 + ((size_t)(i0 + row)*L_SEQ + jn + j)*16 + c4,
                        plds_flat + (1 - cur)*1024 + idx);
            }
            asm volatile("s_waitcnt vmcnt(4)" ::: "memory");   // drain chunk ch, keep ch+1 in flight
        } else {
            asm volatile("s_waitcnt vmcnt(0)" ::: "memory");
        }
        ASYNC_BAR();   // buf[cur] visible to all waves

        // early-issue global loads for phases S/A (overlap with phase B)
        float4 kh[12];
        {
            const float4* kp = kh4 + (size_t)(j0 + j_s)*48 + wv*12;
            #pragma unroll
            for (int k4 = 0; k4 < 12; ++k4) kh[k4] = kp[k4];
        }
        float4 vv[4];
        #pragma unroll
        for (int jj = 0; jj < 4; ++jj)
            vv[jj] = v4[(size_t)(j0 + jg_s + 8*jj)*32 + wv*8 + d4];
        float4 gvv[2];
        #pragma unroll
        for (int jj = 0; jj < 2; ++jj)
            gvv[jj] = vg4[(size_t)(j0 + jg_g + 16*jj)*12 + wv*3 + g4c];

        // ---- phase B: bias partials; wave wv covers c-quarter for its (r_b,j_b) ----
        {
            float bx=0.f, by=0.f, bz=0.f, bw=0.f;
            #pragma unroll
            for (int cp = 0; cp < 4; ++cp) {
                int c4 = (wv << 2) + cp;
                int sw = c4 ^ (j_b & 7);
                float4 pv = pair_lds[cur][r_b][j_b][sw];
                float4 w0 = wb_lds[c4*4+0], w1 = wb_lds[c4*4+1], w2 = wb_lds[c4*4+2], w3 = wb_lds[c4*4+3];
                bx += pv.x*w0.x + pv.y*w1.x + pv.z*w2.x + pv.w*w3.x;
                by += pv.x*w0.y + pv.y*w1.y + pv.z*w2.y + pv.w*w3.y;
                bz += pv.x*w0.z + pv.y*w1.z + pv.z*w2.z + pv.w*w3.z;
                bw += pv.x*w0.w + pv.y*w1.w + pv.z*w2.w + pv.w*w3.w;
            }
            bias_part[wv][r_b][j_b][0] = bx; bias_part[wv][r_b][j_b][1] = by;
            bias_part[wv][r_b][j_b][2] = bz; bias_part[wv][r_b][j_b][3] = bw;
        }
        ASYNC_BAR();

        // ---- phase S: logit (48-dot) + bias + online softmax (lane=(r_s,j_s), head wv) ----
        {
            float d = 0.f;
            #pragma unroll
            for (int k4 = 0; k4 < 12; ++k4) {
                float4 q = qhat_lds[r_s][wv][k4];
                d = fmaf(kh[k4].x, q.x, d); d = fmaf(kh[k4].y, q.y, d);
                d = fmaf(kh[k4].z, q.z, d); d = fmaf(kh[k4].w, q.w, d);
            }
            float bias = bias_part[0][r_s][j_s][wv] + bias_part[1][r_s][j_s][wv]
                       + bias_part[2][r_s][j_s][wv] + bias_part[3][r_s][j_s][wv];
            float logit = d + bias;
            float cmax = logit;
            #pragma unroll
            for (int off = 2; off < 64; off <<= 1) cmax = fmaxf(cmax, __shfl_xor(cmax, off));
            float mn = fmaxf(m_run, cmax);
            float alpha = __expf(m_run - mn);
            float p = __expf(logit - mn);
            float ps = p;
            #pragma unroll
            for (int off = 2; off < 64; off <<= 1) ps += __shfl_xor(ps, off);
            l_run = l_run * alpha + ps;
            m_run = mn;
            p_lds[wv][r_s][j_s] = p;
            if (j_s == 0) alpha_lds[wv][r_s] = alpha;
        }
        ASYNC_BAR();

        // ---- phase A: rescale + accumulate ----
        {
            float al[4][2];
            #pragma unroll
            for (int h = 0; h < 4; ++h) { al[h][0] = alpha_lds[h][0]; al[h][1] = alpha_lds[h][1]; }
            #pragma unroll
            for (int r = 0; r < 2; ++r) {
                #pragma unroll
                for (int h = 0; h < 4; ++h) {
                    float a = al[h][r];
                    accp[r][h].x *= a; accp[r][h].y *= a; accp[r][h].z *= a; accp[r][h].w *= a;
                }
                float a = al[wv][r];
                accs[r].x *= a; accs[r].y *= a; accs[r].z *= a; accs[r].w *= a;
                accg[r].x *= a; accg[r].y *= a; accg[r].z *= a; accg[r].w *= a;
            }
            // o_pair: c4 = wv*4 + c4p, j = jg_p + 16*jj
            #pragma unroll
            for (int jj = 0; jj < 2; ++jj) {
                int j = jg_p + 16*jj;
                int sw = ((wv << 2) + c4p) ^ (j & 7);
                #pragma unroll
                for (int r = 0; r < 2; ++r) {
                    float4 pv = pair_lds[cur][r][j][sw];
                    float p0 = p_lds[0][r][j], p1 = p_lds[1][r][j];
                    float p2 = p_lds[2][r][j], p3 = p_lds[3][r][j];
                    accp[r][0].x = fmaf(p0, pv.x, accp[r][0].x); accp[r][0].y = fmaf(p0, pv.y, accp[r][0].y);
                    accp[r][0].z = fmaf(p0, pv.z, accp[r][0].z); accp[r][0].w = fmaf(p0, pv.w, accp[r][0].w);
                    accp[r][1].x = fmaf(p1, pv.x, accp[r][1].x); accp[r][1].y = fmaf(p1, pv.y, accp[r][1].y);
                    accp[r][1].z = fmaf(p1, pv.z, accp[r][1].z); accp[r][1].w = fmaf(p1, pv.w, accp[r][1].w);
                    accp[r][2].x = fmaf(p2, pv.x, accp[r][2].x); accp[r][2].y = fmaf(p2, pv.y, accp[r][2].y);
                    accp[r][2].z = fmaf(p2, pv.z, accp[r][2].z); accp[r][2].w = fmaf(p2, pv.w, accp[r][2].w);
                    accp[r][3].x = fmaf(p3, pv.x, accp[r][3].x); accp[r][3].y = fmaf(p3, pv.y, accp[r][3].y);
                    accp[r][3].z = fmaf(p3, pv.z, accp[r][3].z); accp[r][3].w = fmaf(p3, pv.w, accp[r][3].w);
                }
            }
            // o_s: head wv
            #pragma unroll
            for (int jj = 0; jj < 4; ++jj) {
                int j = jg_s + 8*jj;
                float pa = p_lds[wv][0][j], pb = p_lds[wv][1][j];
                accs[0].x = fmaf(pa, vv[jj].x, accs[0].x); accs[0].y = fmaf(pa, vv[jj].y, accs[0].y);
                accs[0].z = fmaf(pa, vv[jj].z, accs[0].z); accs[0].w = fmaf(pa, vv[jj].w, accs[0].w);
                accs[1].x = fmaf(pb, vv[jj].x, accs[1].x); accs[1].y = fmaf(pb, vv[jj].y, accs[1].y);
                accs[1].z = fmaf(pb, vv[jj].z, accs[1].z); accs[1].w = fmaf(pb, vv[jj].w, accs[1].w);
            }
            // o_pt_g: head wv
            #pragma unroll
            for (int jj = 0; jj < 2; ++jj) {
                int j = jg_g + 16*jj;
                float pa = p_lds[wv][0][j], pb = p_lds[wv][1][j];
                accg[0].x = fmaf(pa, gvv[jj].x, accg[0].x); accg[0].y = fmaf(pa, gvv[jj].y, accg[0].y);
                accg[0].z = fmaf(pa, gvv[jj].z, accg[0].z); accg[0].w = fmaf(pa, gvv[jj].w, accg[0].w);
                accg[1].x = fmaf(pb, gvv[jj].x, accg[1].x); accg[1].y = fmaf(pb, gvv[jj].y, accg[1].y);
                accg[1].z = fmaf(pb, gvv[jj].z, accg[1].z); accg[1].w = fmaf(pb, gvv[jj].w, accg[1].w);
            }
        }
    }

    // ---- epilogue ----
    #pragma unroll
    for (int r = 0; r < 2; ++r) {
        #pragma unroll
        for (int h = 0; h < 4; ++h) {
            #pragma unroll
            for (int off = 1; off < 16; off <<= 1) {   // reduce over jg_p = lane&15
                accp[r][h].x += __shfl_xor(accp[r][h].x, off);
                accp[r][h].y += __shfl_xor(accp[r][h].y, off);
                accp[r][h].z += __shfl_xor(accp[r][h].z, off);
                accp[r][h].w += __shfl_xor(accp[r][h].w, off);
            }
        }
        #pragma unroll
        for (int off = 8; off < 64; off <<= 1) {       // reduce over jg_s
            accs[r].x += __shfl_xor(accs[r].x, off); accs[r].y += __shfl_xor(accs[r].y, off);
            accs[r].z += __shfl_xor(accs[r].z, off); accs[r].w += __shfl_xor(accs[r].w, off);
        }
        #pragma unroll
        for (int off = 4; off < 64; off <<= 1) {       // reduce over jg_g
            accg[r].x += __shfl_xor(accg[r].x, off); accg[r].y += __shfl_xor(accg[r].y, off);
            accg[r].z += __shfl_xor(accg[r].z, off); accg[r].w += __shfl_xor(accg[r].w, off);
        }
    }
    if (lane < 2) l_lds[wv][lane] = l_run;   // lanes 0 (r=0) / 1 (r=1) hold row's l
    __syncthreads();
    float invl[4][2];
    #pragma unroll
    for (int h = 0; h < 4; ++h) { invl[h][0] = 1.f / l_lds[h][0]; invl[h][1] = 1.f / l_lds[h][1]; }

    if (lane < 8) {
        #pragma unroll
        for (int r = 0; r < 2; ++r) {
            float sc = invl[wv][r];
            int base = wv*32 + lane*4;
            u_lds[r][base+0] = accs[r].x*sc; u_lds[r][base+1] = accs[r].y*sc;
            u_lds[r][base+2] = accs[r].z*sc; u_lds[r][base+3] = accs[r].w*sc;
        }
    }
    if ((lane & 15) == 0) {
        int c4 = wv*4 + (lane >> 4);
        #pragma unroll
        for (int r = 0; r < 2; ++r)
            #pragma unroll
            for (int h = 0; h < 4; ++h) {
                float sc = invl[h][r];
                int base = 128 + h*64 + c4*4;
                u_lds[r][base+0] = accp[r][h].x*sc; u_lds[r][base+1] = accp[r][h].y*sc;
                u_lds[r][base+2] = accp[r][h].z*sc; u_lds[r][base+3] = accp[r][h].w*sc;
            }
    }
    if (lane < 3) {
        #pragma unroll
        for (int r = 0; r < 2; ++r) {
            float sc = invl[wv][r];
            og_lds[r][wv][lane*4+0] = accg[r].x*sc; og_lds[r][wv][lane*4+1] = accg[r].y*sc;
            og_lds[r][wv][lane*4+2] = accg[r].z*sc; og_lds[r][wv][lane*4+3] = accg[r].w*sc;
        }
    }
    __syncthreads();

    if (t < 32) {
        int r = t >> 4, idx = t & 15, h = idx >> 2, p = idx & 3;
        int ii = i0 + r;
        float R[3][3], tt[3];
        #pragma unroll
        for (int x = 0; x < 3; ++x) {
            #pragma unroll
            for (int y = 0; y < 3; ++y) R[x][y] = T[ii*16 + x*4 + y];
            tt[x] = T[ii*16 + x*4 + 3];
        }
        float v0 = og_lds[r][h][p*3+0] - tt[0];
        float v1 = og_lds[r][h][p*3+1] - tt[1];
        float v2 = og_lds[r][h][p*3+2] - tt[2];
        float n2 = 0.f;
        #pragma unroll
        for (int x = 0; x < 3; ++x) {
            float o = R[0][x]*v0 + R[1][x]*v1 + R[2][x]*v2;
            u_lds[r][384 + h*12 + p*3 + x] = o;
            n2 += o*o;
        }
        u_lds[r][432 + h*4 + p] = sqrtf(n2);
    }
    __syncthreads();

    {
        int r = t >> 7, d = t & 127;
        int ii = i0 + r;
        float acc = single[ii*DM + d] + b_out[d];
        const float4* u4 = (const float4*)u_lds[r];
        #pragma unroll 4
        for (int k4 = 0; k4 < 112; ++k4) {
            float4 u = u4[k4];
            const float* wp = Wout + (size_t)(k4*4)*128 + d;
            acc = fmaf(u.x, wp[0],   acc);
            acc = fmaf(u.y, wp[128], acc);
            acc = fmaf(u.z, wp[256], acc);
            acc = fmaf(u.w, wp[384], acc);
        }
        out[ii*DM + d] = acc;
    }
}

extern "C" void kernel_launch(void* const* d_in, const int* in_sizes, int n_in,
                              void* d_out, int out_size, void* d_ws, size_t ws_size,
                              hipStream_t stream)
{
    const float* single = (const float*)d_in[0];
    const float* pair   = (const float*)d_in[1];
    const float* T      = (const float*)d_in[2];
    const float* w_C    = (const float*)d_in[3];
    const float* ln_g   = (const float*)d_in[4];
    const float* ln_b   = (const float*)d_in[5];
    const float* Wq     = (const float*)d_in[6];
    const float* Wk     = (const float*)d_in[7];
    const float* Wv     = (const float*)d_in[8];
    const float* Wqpt   = (const float*)d_in[9];
    const float* Wkpt   = (const float*)d_in[10];
    const float* Wvpt   = (const float*)d_in[11];
    const float* Wb     = (const float*)d_in[12];
    const float* Wout   = (const float*)d_in[13];
    const float* b_out  = (const float*)d_in[14];
    float* out = (float*)d_out;
    float* ws  = (float*)d_ws;

    ipa_prep<<<256, 256, 0, stream>>>(single, T, w_C, ln_g, ln_b, Wq, Wk, Wv, Wqpt, Wkpt, Wvpt, ws);
    ipa_attn<<<512, 256, 0, stream>>>(single, pair, T, Wb, Wout, b_out, ws, out);
}